// Round 8
// baseline (189.640 us; speedup 1.0000x reference)
//
#include <hip/hip_runtime.h>
#include <hip/hip_bf16.h>
#include <stdint.h>

// B=4, S=8192, E=1024, heads=16 -> math collapses to:
//   Q = x @ W1[0:1024].T ; A = per-64-col-block softmax(Q/4) ; out = A @ W2.T
static constexpr int MTOT = 32768;
static constexpr int KD   = 1024;
static constexpr int ND   = 1024;

static constexpr int BM = 256, BN = 256, BK = 64;
static constexpr int NT = KD / BK;              // 16 K-tiles (even)
static constexpr int BUF_BYTES = 65536;         // per-buffer: A 32K + B 32K
static constexpr int BOFF = 32768;              // B offset within buffer
static constexpr int HALF = 16384;              // one unit (128 rows x 64 cols bf16)

typedef __bf16 bf16x8 __attribute__((ext_vector_type(8)));
typedef float  f32x4  __attribute__((ext_vector_type(4)));

__device__ __forceinline__ unsigned short f2bf_rne(float f) {
  union { float f; uint32_t u; } c; c.f = f;
  uint32_t u = c.u;
  return (unsigned short)((u + 0x7fffu + ((u >> 16) & 1u)) >> 16);
}

__global__ void cast_f32_to_bf16(const float* __restrict__ src,
                                 unsigned short* __restrict__ dst, int n4) {
  int idx = blockIdx.x * blockDim.x + threadIdx.x;
  int stride = gridDim.x * blockDim.x;
  for (int i = idx; i < n4; i += stride) {
    float4 v = reinterpret_cast<const float4*>(src)[i];
    ushort4 o;
    o.x = f2bf_rne(v.x); o.y = f2bf_rne(v.y);
    o.z = f2bf_rne(v.z); o.w = f2bf_rne(v.w);
    reinterpret_cast<ushort4*>(dst)[i] = o;
  }
}

__device__ __forceinline__ void gload_lds16(const void* g, void* lds) {
  __builtin_amdgcn_global_load_lds(
      (const __attribute__((address_space(1))) unsigned int*)g,
      (__attribute__((address_space(3))) unsigned int*)lds, 16, 0, 0);
}

// r7 structure (proven 87 us/GEMM): 256x256 tile, BK=64, 8 waves (2Mx4N),
// 128 KiB double-buffered LDS, counted vmcnt (never 0 in loop), T1 XCD
// swizzle, T2 LDS swizzle, 16x16x32 MFMA, setprio around MFMA clusters,
// 3 barriers/K-tile {P2-end, P4-pre(post-vmcnt), P4-end}.
// r8 change: MFMA cluster issued ks-OUTER so 8 independent accumulators
// separate any same-acc reuse (kills dependent-MFMA issue stalls).
template <int SOFTMAX>
__global__ __launch_bounds__(512, 2)
void gemm8(const unsigned short* __restrict__ A,
           const unsigned short* __restrict__ Bm,
           void* __restrict__ Cout) {
  extern __shared__ __align__(16) char ldsc[];

  const int tid  = threadIdx.x;
  const int lane = tid & 63;
  const int wid  = tid >> 6;
  const int wm = wid >> 2, wn = wid & 3;       // wave tile: 128 rows x 64 cols
  const int fr = lane & 15, fq = lane >> 4;

  // T1: bijective XCD swizzle (512 blocks, 8 XCDs, 64 blocks/chunk).
  const int bid0 = blockIdx.x;
  const int bid  = ((bid0 & 7) << 6) | (bid0 >> 3);
  const int brow = (bid >> 2) * BM;
  const int bcol = (bid & 3) * BN;

  // staging: linear LDS dest + inverse-swizzled global src (rule #21).
  const int srow  = tid >> 3;                              // 0..63
  const int sslot = (tid & 7) ^ (srow & 7);
  const unsigned short* gA = A  + (size_t)(brow + srow) * KD + sslot * 8;
  const unsigned short* gB = Bm + (size_t)(bcol + srow) * KD + sslot * 8;

  f32x4  acc[8][4] = {};
  bf16x8 a0[4][2], a1[4][2], bA[2][2], bB[2][2];

  auto STAGE = [&](const unsigned short* g, int h, int kt, int b, int opOff) {
    const unsigned short* gu = g + (size_t)(h * 128) * KD + kt * BK;
    char* du = ldsc + b * BUF_BYTES + opOff + h * HALF + (wid << 10);
    gload_lds16(gu, du);
    gload_lds16(gu + (size_t)64 * KD, du + 8192);
  };

  auto rdA = [&](int b, bf16x8 (*dst)[2], int mBase) {
    const char* base = ldsc + b * BUF_BYTES + wm * HALF;
    #pragma unroll
    for (int mm = 0; mm < 4; ++mm) {
      const int r = (mBase + mm) * 16 + fr;
      #pragma unroll
      for (int ks = 0; ks < 2; ++ks)
        dst[mm][ks] = *(const bf16x8*)(base + (r << 7) +
                        ((ks * 64 + fq * 16) ^ ((r & 7) << 4)));
    }
  };
  auto rdB = [&](int b, int nBase, bf16x8 (*dst)[2]) {
    const char* base = ldsc + b * BUF_BYTES + BOFF + (wn >> 1) * HALF;
    #pragma unroll
    for (int nn = 0; nn < 2; ++nn) {
      const int r = (wn & 1) * 64 + (nBase + nn) * 16 + fr;
      #pragma unroll
      for (int ks = 0; ks < 2; ++ks)
        dst[nn][ks] = *(const bf16x8*)(base + (r << 7) +
                       ((ks * 64 + fq * 16) ^ ((r & 7) << 4)));
    }
  };
  // ks-OUTER: 8 independent accumulators between same-acc reuse.
  auto MFMA16 = [&](int mBase, int nBase, bf16x8 (*af)[2], bf16x8 (*bf)[2]) {
    __builtin_amdgcn_s_setprio(1);
    #pragma unroll
    for (int ks = 0; ks < 2; ++ks)
      #pragma unroll
      for (int mm = 0; mm < 4; ++mm)
        #pragma unroll
        for (int nn = 0; nn < 2; ++nn)
          acc[mBase + mm][nBase + nn] = __builtin_amdgcn_mfma_f32_16x16x32_bf16(
              af[mm][ks], bf[nn][ks], acc[mBase + mm][nBase + nn], 0, 0, 0);
    __builtin_amdgcn_s_setprio(0);
  };

  // One K-tile step with compile-time buffer parity. Barriers:
  //  P2-end, P4-pre(post-vmcnt), P4-end (hazard proofs in r7 notes).
  auto tileStep = [&](int T, int cur, int nxt) {
    const int tp1 = (T + 1 < NT) ? T + 1 : NT - 1;
    const int tp2 = (T + 2 < NT) ? T + 2 : NT - 1;

    // P1 — staged region nxt.B01 last read at T-1 P4 (before T-1 P4-end).
    rdA(cur, a0, 0);
    STAGE(gB, 0, tp1, nxt, BOFF);
    MFMA16(0, 0, a0, bA);

    // P2 — staged region nxt.B23 last read at T-1 P3 (before T-1 P4-pre).
    rdA(cur, a1, 4);
    STAGE(gB, 1, tp1, nxt, BOFF);
    MFMA16(4, 0, a1, bA);
    __builtin_amdgcn_s_barrier();            // P2-end: all cur.A reads retired

    // P3 — staged region cur.A0 last read at P1/P2 (before P2-end).
    rdB(cur, 2, bB);
    STAGE(gA, 0, tp2, cur, 0);
    MFMA16(4, 2, a1, bB);

    // P4 — staged region cur.A1 last read at P1/P2 (before P2-end).
    STAGE(gA, 1, tp2, cur, 0);
    asm volatile("s_waitcnt vmcnt(4)" ::: "memory"); // retires B(T+1); A(T+2) in flight
    __builtin_amdgcn_s_barrier();            // P4-pre: tile T+1 visible to all
    rdB(nxt, 0, bA);                         // tile T+1 b01; overlaps MFMA below
    MFMA16(0, 2, a0, bB);
    __builtin_amdgcn_s_barrier();            // P4-end: cur.B01-read retirement fence
  };

  // --- prologue: tile0 (4 units) + A halves of tile1 ---
  STAGE(gA, 0, 0, 0, 0);    STAGE(gA, 1, 0, 0, 0);
  STAGE(gB, 0, 0, 0, BOFF); STAGE(gB, 1, 0, 0, BOFF);
  STAGE(gA, 0, 1, 1, 0);    STAGE(gA, 1, 1, 1, 0);
  asm volatile("s_waitcnt vmcnt(4)" ::: "memory");   // tile0 landed; A(1) in flight
  __builtin_amdgcn_s_barrier();
  rdB(0, 0, bA);                                     // b01 of tile 0

  for (int T = 0; T < NT; T += 2) {
    tileStep(T,     0, 1);
    tileStep(T + 1, 1, 0);
  }

  if constexpr (SOFTMAX) {
    // logits = acc/4; softmax over the wave's 64-col block (= one head block)
    unsigned short* attn = reinterpret_cast<unsigned short*>(Cout);
    constexpr float CEXP = 0.25f * 1.44269504088896340736f; // log2(e)/4
    #pragma unroll
    for (int m = 0; m < 8; ++m) {
      const int row = brow + wm * 128 + m * 16 + fq * 4;
      #pragma unroll
      for (int j = 0; j < 4; ++j) {
        float v0 = acc[m][0][j], v1 = acc[m][1][j];
        float v2 = acc[m][2][j], v3 = acc[m][3][j];
        float mx = fmaxf(fmaxf(v0, v1), fmaxf(v2, v3));
        #pragma unroll
        for (int s = 1; s < 16; s <<= 1) mx = fmaxf(mx, __shfl_xor(mx, s, 64));
        float p0 = exp2f((v0 - mx) * CEXP);
        float p1 = exp2f((v1 - mx) * CEXP);
        float p2 = exp2f((v2 - mx) * CEXP);
        float p3 = exp2f((v3 - mx) * CEXP);
        float sm = p0 + p1 + p2 + p3;
        #pragma unroll
        for (int s = 1; s < 16; s <<= 1) sm += __shfl_xor(sm, s, 64);
        const float inv = 1.0f / sm;
        unsigned short* dst =
            attn + (size_t)(row + j) * ND + (bcol + wn * 64 + fr);
        dst[0]  = f2bf_rne(p0 * inv);
        dst[16] = f2bf_rne(p1 * inv);
        dst[32] = f2bf_rne(p2 * inv);
        dst[48] = f2bf_rne(p3 * inv);
      }
    }
  } else {
    float* Cf = reinterpret_cast<float*>(Cout);
    #pragma unroll
    for (int m = 0; m < 8; ++m) {
      const int row = brow + wm * 128 + m * 16 + fq * 4;
      #pragma unroll
      for (int n = 0; n < 4; ++n) {
        const int col = bcol + wn * 64 + n * 16 + fr;
        #pragma unroll
        for (int j = 0; j < 4; ++j)
          Cf[(size_t)(row + j) * ND + col] = acc[m][n][j];
      }
    }
  }
}

extern "C" void kernel_launch(void* const* d_in, const int* in_sizes, int n_in,
                              void* d_out, int out_size, void* d_ws, size_t ws_size,
                              hipStream_t stream) {
  const float* x  = (const float*)d_in[0];   // [4,8192,1024] f32
  const float* W1 = (const float*)d_in[1];   // [3072,1024]  f32 (rows 0..1023 = Wq)
  const float* W2 = (const float*)d_in[2];   // [1024,1024]  f32
  float* out = (float*)d_out;

  char* ws = (char*)d_ws;
  unsigned short* xb   = (unsigned short*)(ws);
  unsigned short* w1b  = (unsigned short*)(ws + (size_t)67108864);
  unsigned short* w2b  = (unsigned short*)(ws + (size_t)69206016);
  unsigned short* attn = (unsigned short*)(ws + (size_t)71303168);

  hipFuncSetAttribute(reinterpret_cast<const void*>(gemm8<1>),
                      hipFuncAttributeMaxDynamicSharedMemorySize, 131072);
  hipFuncSetAttribute(reinterpret_cast<const void*>(gemm8<0>),
                      hipFuncAttributeMaxDynamicSharedMemorySize, 131072);

  cast_f32_to_bf16<<<2048, 256, 0, stream>>>(x,  xb,  MTOT * KD / 4);
  cast_f32_to_bf16<<<512,  256, 0, stream>>>(W1, w1b, KD * KD / 4);
  cast_f32_to_bf16<<<512,  256, 0, stream>>>(W2, w2b, KD * KD / 4);

  const int nblk = (MTOT / BM) * (ND / BN);   // 128 * 4 = 512
  gemm8<1><<<nblk, 512, 131072, stream>>>(xb, w1b, (void*)attn);
  gemm8<0><<<nblk, 512, 131072, stream>>>(attn, w2b, (void*)out);
}

// Round 9
// 189.313 us; speedup vs baseline: 1.0017x; 1.0017x over previous
//
#include <hip/hip_runtime.h>
#include <hip/hip_bf16.h>
#include <stdint.h>

// B=4, S=8192, E=1024, heads=16 -> math collapses to:
//   Q = x @ W1[0:1024].T ; A = per-64-col-block softmax(Q/4) ; out = A @ W2.T
static constexpr int MTOT = 32768;
static constexpr int KD   = 1024;
static constexpr int ND   = 1024;

static constexpr int BM = 256, BN = 256, BK = 64;
static constexpr int NT = KD / BK;              // 16 K-tiles (even)
static constexpr int BUF_BYTES = 65536;         // per-buffer: A 32K + B 32K
static constexpr int BOFF = 32768;              // B offset within buffer
static constexpr int HALF = 16384;              // one unit (128 rows x 64 cols bf16)

typedef __bf16 bf16x8 __attribute__((ext_vector_type(8)));
typedef float  f32x4  __attribute__((ext_vector_type(4)));

__device__ __forceinline__ unsigned short f2bf_rne(float f) {
  union { float f; uint32_t u; } c; c.f = f;
  uint32_t u = c.u;
  return (unsigned short)((u + 0x7fffu + ((u >> 16) & 1u)) >> 16);
}

__global__ void cast_f32_to_bf16(const float* __restrict__ src,
                                 unsigned short* __restrict__ dst, int n4) {
  int idx = blockIdx.x * blockDim.x + threadIdx.x;
  int stride = gridDim.x * blockDim.x;
  for (int i = idx; i < n4; i += stride) {
    float4 v = reinterpret_cast<const float4*>(src)[i];
    ushort4 o;
    o.x = f2bf_rne(v.x); o.y = f2bf_rne(v.y);
    o.z = f2bf_rne(v.z); o.w = f2bf_rne(v.w);
    reinterpret_cast<ushort4*>(dst)[i] = o;
  }
}

__device__ __forceinline__ void gload_lds16(const void* g, void* lds) {
  __builtin_amdgcn_global_load_lds(
      (const __attribute__((address_space(1))) unsigned int*)g,
      (__attribute__((address_space(3))) unsigned int*)lds, 16, 0, 0);
}

// r7 skeleton (proven 87 us/GEMM, 0 conflicts): 256x256 tile, BK=64, 8 waves
// (2Mx4N), 128 KiB double-buffered LDS, counted vmcnt (never 0 in loop),
// T1 XCD swizzle, T2 LDS swizzle, 16x16x32 MFMA, setprio, 3 barriers/K-tile
// {P2-end, P4-pre(post-vmcnt), P4-end}.
// r9 change: front-loaded reads -- P1 reads a0+a1 and stages B0+B1(T+1);
// P2 and P4 are pure-MFMA phases (operands already in registers).
template <int SOFTMAX>
__global__ __launch_bounds__(512, 2)
void gemm8(const unsigned short* __restrict__ A,
           const unsigned short* __restrict__ Bm,
           void* __restrict__ Cout) {
  extern __shared__ __align__(16) char ldsc[];

  const int tid  = threadIdx.x;
  const int lane = tid & 63;
  const int wid  = tid >> 6;
  const int wm = wid >> 2, wn = wid & 3;       // wave tile: 128 rows x 64 cols
  const int fr = lane & 15, fq = lane >> 4;

  // T1: bijective XCD swizzle (512 blocks, 8 XCDs, 64 blocks/chunk).
  const int bid0 = blockIdx.x;
  const int bid  = ((bid0 & 7) << 6) | (bid0 >> 3);
  const int brow = (bid >> 2) * BM;
  const int bcol = (bid & 3) * BN;

  // staging: linear LDS dest + inverse-swizzled global src (rule #21).
  const int srow  = tid >> 3;                              // 0..63
  const int sslot = (tid & 7) ^ (srow & 7);
  const unsigned short* gA = A  + (size_t)(brow + srow) * KD + sslot * 8;
  const unsigned short* gB = Bm + (size_t)(bcol + srow) * KD + sslot * 8;

  f32x4  acc[8][4] = {};
  bf16x8 a0[4][2], a1[4][2], bA[2][2], bB[2][2];

  auto STAGE = [&](const unsigned short* g, int h, int kt, int b, int opOff) {
    const unsigned short* gu = g + (size_t)(h * 128) * KD + kt * BK;
    char* du = ldsc + b * BUF_BYTES + opOff + h * HALF + (wid << 10);
    gload_lds16(gu, du);
    gload_lds16(gu + (size_t)64 * KD, du + 8192);
  };

  auto rdA = [&](int b, bf16x8 (*dst)[2], int mBase) {
    const char* base = ldsc + b * BUF_BYTES + wm * HALF;
    #pragma unroll
    for (int mm = 0; mm < 4; ++mm) {
      const int r = (mBase + mm) * 16 + fr;
      #pragma unroll
      for (int ks = 0; ks < 2; ++ks)
        dst[mm][ks] = *(const bf16x8*)(base + (r << 7) +
                        ((ks * 64 + fq * 16) ^ ((r & 7) << 4)));
    }
  };
  auto rdB = [&](int b, int nBase, bf16x8 (*dst)[2]) {
    const char* base = ldsc + b * BUF_BYTES + BOFF + (wn >> 1) * HALF;
    #pragma unroll
    for (int nn = 0; nn < 2; ++nn) {
      const int r = (wn & 1) * 64 + (nBase + nn) * 16 + fr;
      #pragma unroll
      for (int ks = 0; ks < 2; ++ks)
        dst[nn][ks] = *(const bf16x8*)(base + (r << 7) +
                       ((ks * 64 + fq * 16) ^ ((r & 7) << 4)));
    }
  };
  auto MFMA16 = [&](int mBase, int nBase, bf16x8 (*af)[2], bf16x8 (*bf)[2]) {
    __builtin_amdgcn_s_setprio(1);
    #pragma unroll
    for (int ks = 0; ks < 2; ++ks)
      #pragma unroll
      for (int mm = 0; mm < 4; ++mm)
        #pragma unroll
        for (int nn = 0; nn < 2; ++nn)
          acc[mBase + mm][nBase + nn] = __builtin_amdgcn_mfma_f32_16x16x32_bf16(
              af[mm][ks], bf[nn][ks], acc[mBase + mm][nBase + nn], 0, 0, 0);
    __builtin_amdgcn_s_setprio(0);
  };

  // One K-tile step, compile-time buffer parity. Barriers:
  //   P2-end, P4-pre(post-vmcnt), P4-end.
  auto tileStep = [&](int T, int cur, int nxt) {
    const int tp1 = (T + 1 < NT) ? T + 1 : NT - 1;
    const int tp2 = (T + 2 < NT) ? T + 2 : NT - 1;

    // P1 — all cur.A reads + both B(T+1) stages. Staged region nxt.B01 last
    // read T-1 P4 (retired before T-1 P4-end); nxt.B23 last read T-1 P3
    // (retired before its MFMA, thus before T-1 P4-end).
    rdA(cur, a0, 0);
    rdA(cur, a1, 4);
    STAGE(gB, 0, tp1, nxt, BOFF);
    STAGE(gB, 1, tp1, nxt, BOFF);
    MFMA16(0, 0, a0, bA);            // waits only on a0 (counted lgkm)

    // P2 — pure MFMA (a1, bA already in regs; a1 reads retire pre-use).
    MFMA16(4, 0, a1, bA);
    __builtin_amdgcn_s_barrier();            // P2-end: all cur.A reads retired

    // P3 — staged region cur.A0 last read at P1 (before P2-end).
    rdB(cur, 2, bB);
    STAGE(gA, 0, tp2, cur, 0);
    MFMA16(4, 2, a1, bB);

    // P4 — staged region cur.A1 last read at P1 (before P2-end).
    STAGE(gA, 1, tp2, cur, 0);
    // queue: A(T+1)x4, B(T+1)x4, A(T+2)x4 -> vmcnt(4) retires tile T+1,
    // keeps A(T+2) in flight. Never 0 in loop.
    asm volatile("s_waitcnt vmcnt(4)" ::: "memory");
    __builtin_amdgcn_s_barrier();            // P4-pre: tile T+1 visible to all
    rdB(nxt, 0, bA);                         // tile T+1 b01; overlaps MFMA below
    MFMA16(0, 2, a0, bB);
    __builtin_amdgcn_s_barrier();            // P4-end: cur.B01-read retirement fence
  };

  // --- prologue: tile0 (4 units) + A halves of tile1 ---
  STAGE(gA, 0, 0, 0, 0);    STAGE(gA, 1, 0, 0, 0);
  STAGE(gB, 0, 0, 0, BOFF); STAGE(gB, 1, 0, 0, BOFF);
  STAGE(gA, 0, 1, 1, 0);    STAGE(gA, 1, 1, 1, 0);
  asm volatile("s_waitcnt vmcnt(4)" ::: "memory");   // tile0 landed; A(1) in flight
  __builtin_amdgcn_s_barrier();
  rdB(0, 0, bA);                                     // b01 of tile 0

  for (int T = 0; T < NT; T += 2) {
    tileStep(T,     0, 1);
    tileStep(T + 1, 1, 0);
  }

  if constexpr (SOFTMAX) {
    // logits = acc/4; softmax over the wave's 64-col block (= one head block)
    unsigned short* attn = reinterpret_cast<unsigned short*>(Cout);
    constexpr float CEXP = 0.25f * 1.44269504088896340736f; // log2(e)/4
    #pragma unroll
    for (int m = 0; m < 8; ++m) {
      const int row = brow + wm * 128 + m * 16 + fq * 4;
      #pragma unroll
      for (int j = 0; j < 4; ++j) {
        float v0 = acc[m][0][j], v1 = acc[m][1][j];
        float v2 = acc[m][2][j], v3 = acc[m][3][j];
        float mx = fmaxf(fmaxf(v0, v1), fmaxf(v2, v3));
        #pragma unroll
        for (int s = 1; s < 16; s <<= 1) mx = fmaxf(mx, __shfl_xor(mx, s, 64));
        float p0 = exp2f((v0 - mx) * CEXP);
        float p1 = exp2f((v1 - mx) * CEXP);
        float p2 = exp2f((v2 - mx) * CEXP);
        float p3 = exp2f((v3 - mx) * CEXP);
        float sm = p0 + p1 + p2 + p3;
        #pragma unroll
        for (int s = 1; s < 16; s <<= 1) sm += __shfl_xor(sm, s, 64);
        const float inv = 1.0f / sm;
        unsigned short* dst =
            attn + (size_t)(row + j) * ND + (bcol + wn * 64 + fr);
        dst[0]  = f2bf_rne(p0 * inv);
        dst[16] = f2bf_rne(p1 * inv);
        dst[32] = f2bf_rne(p2 * inv);
        dst[48] = f2bf_rne(p3 * inv);
      }
    }
  } else {
    float* Cf = reinterpret_cast<float*>(Cout);
    #pragma unroll
    for (int m = 0; m < 8; ++m) {
      const int row = brow + wm * 128 + m * 16 + fq * 4;
      #pragma unroll
      for (int n = 0; n < 4; ++n) {
        const int col = bcol + wn * 64 + n * 16 + fr;
        #pragma unroll
        for (int j = 0; j < 4; ++j)
          Cf[(size_t)(row + j) * ND + col] = acc[m][n][j];
      }
    }
  }
}

extern "C" void kernel_launch(void* const* d_in, const int* in_sizes, int n_in,
                              void* d_out, int out_size, void* d_ws, size_t ws_size,
                              hipStream_t stream) {
  const float* x  = (const float*)d_in[0];   // [4,8192,1024] f32
  const float* W1 = (const float*)d_in[1];   // [3072,1024]  f32 (rows 0..1023 = Wq)
  const float* W2 = (const float*)d_in[2];   // [1024,1024]  f32
  float* out = (float*)d_out;

  char* ws = (char*)d_ws;
  unsigned short* xb   = (unsigned short*)(ws);
  unsigned short* w1b  = (unsigned short*)(ws + (size_t)67108864);
  unsigned short* w2b  = (unsigned short*)(ws + (size_t)69206016);
  unsigned short* attn = (unsigned short*)(ws + (size_t)71303168);

  hipFuncSetAttribute(reinterpret_cast<const void*>(gemm8<1>),
                      hipFuncAttributeMaxDynamicSharedMemorySize, 131072);
  hipFuncSetAttribute(reinterpret_cast<const void*>(gemm8<0>),
                      hipFuncAttributeMaxDynamicSharedMemorySize, 131072);

  cast_f32_to_bf16<<<2048, 256, 0, stream>>>(x,  xb,  MTOT * KD / 4);
  cast_f32_to_bf16<<<512,  256, 0, stream>>>(W1, w1b, KD * KD / 4);
  cast_f32_to_bf16<<<512,  256, 0, stream>>>(W2, w2b, KD * KD / 4);

  const int nblk = (MTOT / BM) * (ND / BN);   // 128 * 4 = 512
  gemm8<1><<<nblk, 512, 131072, stream>>>(xb, w1b, (void*)attn);
  gemm8<0><<<nblk, 512, 131072, stream>>>(attn, w2b, (void*)out);
}